// Round 1
// baseline (514.077 us; speedup 1.0000x reference)
//
#include <hip/hip_runtime.h>
#include <hip/hip_bf16.h>
#include <math.h>

#define N_NODES 50000
#define E_EDGES 800000
#define E_TOT   850000   // + self loops
#define NEG_SLOPE 0.2f

// ---------------------------------------------------------------------------
// int64 vs int32 edge-index detection: if data is int64 (values < 50000 >= 0),
// every odd 32-bit word is zero. With int32 data those words are random edge
// ids (P(all 2048 zero) ~ 0). flag = 1 -> int64.
// ---------------------------------------------------------------------------
__global__ void k_detect(const unsigned int* __restrict__ ei, int* __restrict__ flag) {
    __shared__ int anynz;
    int t = threadIdx.x;
    if (t == 0) anynz = 0;
    __syncthreads();
    int nz = 0;
    for (int i = t; i < 2048; i += 256)
        nz |= (ei[2 * i + 1] != 0u);
    if (nz) atomicOr(&anynz, 1);
    __syncthreads();
    if (t == 0) *flag = (anynz == 0) ? 1 : 0;
}

__device__ __forceinline__ void edge_nodes(const void* ei, int is64, int e, int& s, int& d) {
    if (e >= E_EDGES) { s = d = e - E_EDGES; return; }   // self loop
    if (is64) {
        const long long* p = (const long long*)ei;
        s = (int)p[e]; d = (int)p[E_EDGES + e];
    } else {
        const int* p = (const int*)ei;
        s = p[e]; d = p[E_EDGES + e];
    }
}

// ---------------------------------------------------------------------------
// CSR build: histogram -> scan -> fill
// ---------------------------------------------------------------------------
__global__ void k_count(const void* __restrict__ ei, const int* __restrict__ flag,
                        int* __restrict__ counts) {
    int e = blockIdx.x * 256 + threadIdx.x;
    if (e >= E_TOT) return;
    int s, d;
    edge_nodes(ei, *flag, e, s, d);
    atomicAdd(&counts[d], 1);
}

// single block, 1024 threads; in-place counts -> exclusive offsets (+ cursor copy)
__global__ __launch_bounds__(1024) void k_scan(int* __restrict__ offs, int* __restrict__ cursor) {
    __shared__ int sums[1024];
    const int t = threadIdx.x;
    const int CH = 49;                       // 1024*49 = 50176 >= 50001
    int base = t * CH;
    int loc[CH];
    int s = 0;
#pragma unroll
    for (int i = 0; i < CH; ++i) {
        int idx = base + i;
        int v = (idx < N_NODES) ? offs[idx] : 0;
        loc[i] = v; s += v;
    }
    sums[t] = s;
    __syncthreads();
    for (int off = 1; off < 1024; off <<= 1) {
        int v = (t >= off) ? sums[t - off] : 0;
        __syncthreads();
        sums[t] += v;
        __syncthreads();
    }
    int run = (t > 0) ? sums[t - 1] : 0;     // exclusive prefix of this chunk
#pragma unroll
    for (int i = 0; i < CH; ++i) {
        int idx = base + i;
        if (idx <= N_NODES) {
            offs[idx] = run;
            if (idx < N_NODES) cursor[idx] = run;
        }
        run += loc[i];
    }
}

__global__ void k_fill(const void* __restrict__ ei, const int* __restrict__ flag,
                       int* __restrict__ cursor, int* __restrict__ csr_src) {
    int e = blockIdx.x * 256 + threadIdx.x;
    if (e >= E_TOT) return;
    int s, d;
    edge_nodes(ei, *flag, e, s, d);
    int pos = atomicAdd(&cursor[d], 1);
    csr_src[pos] = s;
}

// ---------------------------------------------------------------------------
// K1: h1 = x @ W1  (50000x128 @ 128x64) + per-node attention halves.
// 64 nodes/block, 256 threads, 4 node x 4 out register tile.
// ---------------------------------------------------------------------------
__global__ __launch_bounds__(256) void k1_transform(
        const float* __restrict__ x, const float* __restrict__ W1,
        const float* __restrict__ a1s, const float* __restrict__ a1d,
        float* __restrict__ h1, float* __restrict__ as1, float* __restrict__ ad1) {
    __shared__ float ws[128 * 64];           // 32 KB
    __shared__ float xs[64 * 132];           // 33.8 KB (pad 132 keeps 16B-aligned rows, breaks conflicts)
    const int t  = threadIdx.x;
    const int nb = blockIdx.x * 64;
    // stage W1 (row-major [k][64])
    for (int i = t * 4; i < 128 * 64; i += 1024)
        *(float4*)&ws[i] = *(const float4*)&W1[i];
    // stage x rows
    for (int i = t * 4; i < 64 * 128; i += 1024) {
        int n = i >> 7, k = i & 127;
        float4 v = make_float4(0.f, 0.f, 0.f, 0.f);
        if (nb + n < N_NODES) v = *(const float4*)&x[(size_t)(nb + n) * 128 + k];
        *(float4*)&xs[n * 132 + k] = v;
    }
    __syncthreads();

    const int oq = t & 15;                   // out quad (outs oq*4..+3)
    const int nq = t >> 4;                   // node quad (nodes nq*4..+3)
    float4 acc[4];
#pragma unroll
    for (int i = 0; i < 4; ++i) acc[i] = make_float4(0.f, 0.f, 0.f, 0.f);

    for (int k = 0; k < 128; k += 4) {
        float4 wv0 = *(float4*)&ws[(k + 0) * 64 + oq * 4];
        float4 wv1 = *(float4*)&ws[(k + 1) * 64 + oq * 4];
        float4 wv2 = *(float4*)&ws[(k + 2) * 64 + oq * 4];
        float4 wv3 = *(float4*)&ws[(k + 3) * 64 + oq * 4];
#pragma unroll
        for (int i = 0; i < 4; ++i) {
            float4 xv = *(float4*)&xs[(nq * 4 + i) * 132 + k];
            acc[i].x += xv.x * wv0.x + xv.y * wv1.x + xv.z * wv2.x + xv.w * wv3.x;
            acc[i].y += xv.x * wv0.y + xv.y * wv1.y + xv.z * wv2.y + xv.w * wv3.y;
            acc[i].z += xv.x * wv0.z + xv.y * wv1.z + xv.z * wv2.z + xv.w * wv3.z;
            acc[i].w += xv.x * wv0.w + xv.y * wv1.w + xv.z * wv2.w + xv.w * wv3.w;
        }
    }
    __syncthreads();                          // xs dead -> reuse as hs[64][68]
#pragma unroll
    for (int i = 0; i < 4; ++i) {
        int n = nq * 4 + i;
        *(float4*)&xs[n * 68 + oq * 4] = acc[i];
        if (nb + n < N_NODES)
            *(float4*)&h1[(size_t)(nb + n) * 64 + oq * 4] = acc[i];
    }
    __syncthreads();
    // alpha halves: 64 nodes x 8 heads = 512 pairs, 2 per thread
    for (int p = t; p < 512; p += 256) {
        int n = p >> 3, hd = p & 7;
        float ss = 0.f, dd = 0.f;
#pragma unroll
        for (int o = 0; o < 8; ++o) {
            float hv = xs[n * 68 + hd * 8 + o];
            ss += hv * a1s[hd * 8 + o];
            dd += hv * a1d[hd * 8 + o];
        }
        if (nb + n < N_NODES) {
            as1[(nb + n) * 8 + hd] = ss;
            ad1[(nb + n) * 8 + hd] = dd;
        }
    }
}

// ---------------------------------------------------------------------------
// K_agg1: per destination node (one wave, lane = feature 0..63):
//   agg = sum_e exp(lrelu(as[src]+ad[dst])) * h1[src]  / denom ; +b1 ; ELU
// ---------------------------------------------------------------------------
__global__ __launch_bounds__(256) void k_agg1(
        const float* __restrict__ h1, const float* __restrict__ as1,
        const float* __restrict__ ad1, const int* __restrict__ offs,
        const int* __restrict__ csr, const float* __restrict__ b1,
        float* __restrict__ hpost) {
    int wid = (blockIdx.x * 256 + threadIdx.x) >> 6;   // node
    int l   = threadIdx.x & 63;
    if (wid >= N_NODES) return;
    int hd   = l >> 3;
    float ad = ad1[wid * 8 + hd];
    int j0 = offs[wid], j1 = offs[wid + 1];
    float acc = 0.f, den = 0.f;
    int j = j0;
    int sNext = (j < j1) ? csr[j] : 0;
    while (j < j1) {
        int s = sNext;
        ++j;
        sNext = (j < j1) ? csr[j] : 0;        // prefetch next src id
        float as = as1[s * 8 + hd];
        float hv = h1[(size_t)s * 64 + l];
        float e  = as + ad;
        e = (e > 0.f) ? e : NEG_SLOPE * e;
        float ex = __expf(e);
        den += ex;
        acc += ex * hv;
    }
    float v = acc / den + b1[l];
    hpost[(size_t)wid * 64 + l] = (v > 0.f) ? v : expm1f(v);   // ELU
}

// ---------------------------------------------------------------------------
// K2: h2 = hpost @ W2 (64->40) + alpha halves. One wave per node.
// ---------------------------------------------------------------------------
__global__ __launch_bounds__(256) void k2_transform(
        const float* __restrict__ hpost, const float* __restrict__ W2,
        const float* __restrict__ a2s, const float* __restrict__ a2d,
        float* __restrict__ h2, float* __restrict__ as2, float* __restrict__ ad2) {
    __shared__ float ws[64 * 40];            // 10 KB
    __shared__ float rows[4][64];
    int t = threadIdx.x;
    for (int i = t; i < 64 * 40; i += 256) ws[i] = W2[i];
    int w = t >> 6, l = t & 63;
    int n = blockIdx.x * 4 + w;
    float rv = 0.f;
    if (n < N_NODES) rv = hpost[(size_t)n * 64 + l];
    rows[w][l] = rv;
    __syncthreads();
    float acc = 0.f;
    if (l < 40) {
#pragma unroll 8
        for (int k = 0; k < 64; ++k)
            acc += rows[w][k] * ws[k * 40 + l];
    }
    float ps = (l < 40) ? acc * a2s[l] : 0.f;
    float pd = (l < 40) ? acc * a2d[l] : 0.f;
#pragma unroll
    for (int off = 32; off; off >>= 1) {
        ps += __shfl_down(ps, off);
        pd += __shfl_down(pd, off);
    }
    if (n < N_NODES) {
        if (l < 40) h2[(size_t)n * 40 + l] = acc;
        if (l == 0) { as2[n] = ps; ad2[n] = pd; }
    }
}

// ---------------------------------------------------------------------------
// K_agg2: layer-2 aggregate + bias + log_softmax(40). One wave per node.
// ---------------------------------------------------------------------------
__global__ __launch_bounds__(256) void k_agg2(
        const float* __restrict__ h2, const float* __restrict__ as2,
        const float* __restrict__ ad2, const int* __restrict__ offs,
        const int* __restrict__ csr, const float* __restrict__ b2,
        float* __restrict__ out) {
    int wid = (blockIdx.x * 256 + threadIdx.x) >> 6;
    int l   = threadIdx.x & 63;
    if (wid >= N_NODES) return;
    bool act = (l < 40);
    float ad = ad2[wid];
    int j0 = offs[wid], j1 = offs[wid + 1];
    float acc = 0.f, den = 0.f;
    int j = j0;
    int sNext = (j < j1) ? csr[j] : 0;
    while (j < j1) {
        int s = sNext;
        ++j;
        sNext = (j < j1) ? csr[j] : 0;
        float as = as2[s];
        float e  = as + ad;
        e = (e > 0.f) ? e : NEG_SLOPE * e;
        float ex = __expf(e);
        den += ex;
        if (act) acc += ex * h2[(size_t)s * 40 + l];
    }
    float v = act ? (acc / den + b2[l]) : -1e30f;
    // log_softmax over the 40 active lanes
    float m = v;
#pragma unroll
    for (int off = 32; off; off >>= 1) m = fmaxf(m, __shfl_xor(m, off));
    float ex2 = act ? __expf(v - m) : 0.f;
    float s2 = ex2;
#pragma unroll
    for (int off = 32; off; off >>= 1) s2 += __shfl_xor(s2, off);
    if (act) out[(size_t)wid * 40 + l] = v - m - __logf(s2);
}

// ---------------------------------------------------------------------------
extern "C" void kernel_launch(void* const* d_in, const int* in_sizes, int n_in,
                              void* d_out, int out_size, void* d_ws, size_t ws_size,
                              hipStream_t stream) {
    const float* x   = (const float*)d_in[0];
    const void*  ei  = d_in[1];               // int64 or int32, detected on device
    const float* W1  = (const float*)d_in[2];
    const float* a1s = (const float*)d_in[3];
    const float* a1d = (const float*)d_in[4];
    const float* b1  = (const float*)d_in[5];
    const float* W2  = (const float*)d_in[6];
    const float* a2s = (const float*)d_in[7];
    const float* a2d = (const float*)d_in[8];
    const float* b2  = (const float*)d_in[9];
    float* out = (float*)d_out;

    // workspace layout (floats), h2/as2/ad2 overlay h1/as1/ad1 (dead after agg1)
    float* fws   = (float*)d_ws;
    float* h1    = fws + 0;                   // 3,200,000
    float* hpost = fws + 3200000;             // 3,200,000
    float* as1   = fws + 6400000;             //   400,000
    float* ad1   = fws + 6800000;             //   400,000
    float* h2    = h1;                        // 2,000,000 (overlay)
    float* as2   = as1;                       //    50,000 (overlay)
    float* ad2   = ad1;                       //    50,000 (overlay)
    int*   offs   = (int*)(fws + 7200000);    // 50,001 (counts -> offsets in place)
    int*   cursor = offs + (N_NODES + 1);     // 50,000
    int*   csr    = cursor + N_NODES;         // 850,000
    int*   flag   = csr + E_TOT;              // 1

    // zero the histogram
    hipMemsetAsync(offs, 0, (N_NODES + 1) * sizeof(int), stream);

    k_detect<<<1, 256, 0, stream>>>((const unsigned int*)ei, flag);

    int egrid = (E_TOT + 255) / 256;
    k_count<<<egrid, 256, 0, stream>>>(ei, flag, offs);
    k_scan<<<1, 1024, 0, stream>>>(offs, cursor);
    k_fill<<<egrid, 256, 0, stream>>>(ei, flag, cursor, csr);

    k1_transform<<<(N_NODES + 63) / 64, 256, 0, stream>>>(x, W1, a1s, a1d, h1, as1, ad1);

    int ngrid = (N_NODES + 3) / 4;            // 4 waves (nodes) per block
    k_agg1<<<ngrid, 256, 0, stream>>>(h1, as1, ad1, offs, csr, b1, hpost);
    k2_transform<<<ngrid, 256, 0, stream>>>(hpost, W2, a2s, a2d, h2, as2, ad2);
    k_agg2<<<ngrid, 256, 0, stream>>>(h2, as2, ad2, offs, csr, b2, out);
}

// Round 2
// 388.924 us; speedup vs baseline: 1.3218x; 1.3218x over previous
//
#include <hip/hip_runtime.h>
#include <hip/hip_bf16.h>
#include <math.h>

#define N_NODES 50000
#define E_EDGES 800000
#define E_TOT   850000   // + self loops
#define NEG_SLOPE 0.2f

// ---------------------------------------------------------------------------
// int64 vs int32 edge-index detection (values < 50000 -> int64 high words 0)
// ---------------------------------------------------------------------------
__global__ void k_detect(const unsigned int* __restrict__ ei, int* __restrict__ flag) {
    __shared__ int anynz;
    int t = threadIdx.x;
    if (t == 0) anynz = 0;
    __syncthreads();
    int nz = 0;
    for (int i = t; i < 2048; i += 256)
        nz |= (ei[2 * i + 1] != 0u);
    if (nz) atomicOr(&anynz, 1);
    __syncthreads();
    if (t == 0) *flag = (anynz == 0) ? 1 : 0;
}

__device__ __forceinline__ void edge_nodes(const void* ei, int is64, int e, int& s, int& d) {
    if (e >= E_EDGES) { s = d = e - E_EDGES; return; }   // self loop
    if (is64) {
        const long long* p = (const long long*)ei;
        s = (int)p[e]; d = (int)p[E_EDGES + e];
    } else {
        const int* p = (const int*)ei;
        s = p[e]; d = p[E_EDGES + e];
    }
}

// ---------------------------------------------------------------------------
// CSR build: histogram -> scan -> fill
// ---------------------------------------------------------------------------
__global__ void k_count(const void* __restrict__ ei, const int* __restrict__ flag,
                        int* __restrict__ counts) {
    int e = blockIdx.x * 256 + threadIdx.x;
    if (e >= E_TOT) return;
    int s, d;
    edge_nodes(ei, *flag, e, s, d);
    atomicAdd(&counts[d], 1);
}

__global__ __launch_bounds__(1024) void k_scan(int* __restrict__ offs, int* __restrict__ cursor) {
    __shared__ int sums[1024];
    const int t = threadIdx.x;
    const int CH = 49;                       // 1024*49 = 50176 >= 50001
    int base = t * CH;
    int loc[CH];
    int s = 0;
#pragma unroll
    for (int i = 0; i < CH; ++i) {
        int idx = base + i;
        int v = (idx < N_NODES) ? offs[idx] : 0;
        loc[i] = v; s += v;
    }
    sums[t] = s;
    __syncthreads();
    for (int off = 1; off < 1024; off <<= 1) {
        int v = (t >= off) ? sums[t - off] : 0;
        __syncthreads();
        sums[t] += v;
        __syncthreads();
    }
    int run = (t > 0) ? sums[t - 1] : 0;
#pragma unroll
    for (int i = 0; i < CH; ++i) {
        int idx = base + i;
        if (idx <= N_NODES) {
            offs[idx] = run;
            if (idx < N_NODES) cursor[idx] = run;
        }
        run += loc[i];
    }
}

__global__ void k_fill(const void* __restrict__ ei, const int* __restrict__ flag,
                       int* __restrict__ cursor, int* __restrict__ csr_src) {
    int e = blockIdx.x * 256 + threadIdx.x;
    if (e >= E_TOT) return;
    int s, d;
    edge_nodes(ei, *flag, e, s, d);
    int pos = atomicAdd(&cursor[d], 1);
    csr_src[pos] = s;
}

// ---------------------------------------------------------------------------
// K1: h1 = x @ W1 (50000x128 @ 128x64) + per-node attention halves
// ---------------------------------------------------------------------------
__global__ __launch_bounds__(256) void k1_transform(
        const float* __restrict__ x, const float* __restrict__ W1,
        const float* __restrict__ a1s, const float* __restrict__ a1d,
        float* __restrict__ h1, float* __restrict__ as1, float* __restrict__ ad1) {
    __shared__ float ws[128 * 64];
    __shared__ float xs[64 * 132];
    const int t  = threadIdx.x;
    const int nb = blockIdx.x * 64;
    for (int i = t * 4; i < 128 * 64; i += 1024)
        *(float4*)&ws[i] = *(const float4*)&W1[i];
    for (int i = t * 4; i < 64 * 128; i += 1024) {
        int n = i >> 7, k = i & 127;
        float4 v = make_float4(0.f, 0.f, 0.f, 0.f);
        if (nb + n < N_NODES) v = *(const float4*)&x[(size_t)(nb + n) * 128 + k];
        *(float4*)&xs[n * 132 + k] = v;
    }
    __syncthreads();

    const int oq = t & 15;
    const int nq = t >> 4;
    float4 acc[4];
#pragma unroll
    for (int i = 0; i < 4; ++i) acc[i] = make_float4(0.f, 0.f, 0.f, 0.f);

    for (int k = 0; k < 128; k += 4) {
        float4 wv0 = *(float4*)&ws[(k + 0) * 64 + oq * 4];
        float4 wv1 = *(float4*)&ws[(k + 1) * 64 + oq * 4];
        float4 wv2 = *(float4*)&ws[(k + 2) * 64 + oq * 4];
        float4 wv3 = *(float4*)&ws[(k + 3) * 64 + oq * 4];
#pragma unroll
        for (int i = 0; i < 4; ++i) {
            float4 xv = *(float4*)&xs[(nq * 4 + i) * 132 + k];
            acc[i].x += xv.x * wv0.x + xv.y * wv1.x + xv.z * wv2.x + xv.w * wv3.x;
            acc[i].y += xv.x * wv0.y + xv.y * wv1.y + xv.z * wv2.y + xv.w * wv3.y;
            acc[i].z += xv.x * wv0.z + xv.y * wv1.z + xv.z * wv2.z + xv.w * wv3.z;
            acc[i].w += xv.x * wv0.w + xv.y * wv1.w + xv.z * wv2.w + xv.w * wv3.w;
        }
    }
    __syncthreads();
#pragma unroll
    for (int i = 0; i < 4; ++i) {
        int n = nq * 4 + i;
        *(float4*)&xs[n * 68 + oq * 4] = acc[i];
        if (nb + n < N_NODES)
            *(float4*)&h1[(size_t)(nb + n) * 64 + oq * 4] = acc[i];
    }
    __syncthreads();
    for (int p = t; p < 512; p += 256) {
        int n = p >> 3, hd = p & 7;
        float ss = 0.f, dd = 0.f;
#pragma unroll
        for (int o = 0; o < 8; ++o) {
            float hv = xs[n * 68 + hd * 8 + o];
            ss += hv * a1s[hd * 8 + o];
            dd += hv * a1d[hd * 8 + o];
        }
        if (nb + n < N_NODES) {
            as1[(nb + n) * 8 + hd] = ss;
            ad1[(nb + n) * 8 + hd] = dd;
        }
    }
}

// ---------------------------------------------------------------------------
// K_agg1 (fused with layer-2 transform):
//   per node: softmax-aggregate over in-edges (4-wide pipelined gathers),
//   +b1, ELU  -> then in-wave 64->40 transform + alpha2 halves.
// ---------------------------------------------------------------------------
__global__ __launch_bounds__(256) void k_agg1f(
        const float* __restrict__ h1, const float* __restrict__ as1g,
        const float* __restrict__ ad1g, const int* __restrict__ offs,
        const int* __restrict__ csr, const float* __restrict__ b1,
        const float* __restrict__ W2, const float* __restrict__ a2s,
        const float* __restrict__ a2d,
        float* __restrict__ h2p, float* __restrict__ as2, float* __restrict__ ad2) {
    __shared__ float ws[64 * 40];            // 10 KB
    __shared__ float rows[4][64];
    const int t = threadIdx.x;
    for (int i = t; i < 64 * 40; i += 256) ws[i] = W2[i];
    __syncthreads();

    const int w = t >> 6, l = t & 63;
    const int wid = blockIdx.x * 4 + w;
    if (wid >= N_NODES) return;
    const int hd = l >> 3;
    const float ad = ad1g[wid * 8 + hd];
    const int j0 = offs[wid], j1 = offs[wid + 1];
    const int j1m = j1 - 1;

    float acc = 0.f, den = 0.f;
    int c0 = csr[j0];
    int c1 = csr[min(j0 + 1, j1m)];
    int c2 = csr[min(j0 + 2, j1m)];
    int c3 = csr[min(j0 + 3, j1m)];
    for (int j = j0; j < j1; ) {
        const int s0 = c0, s1 = c1, s2 = c2, s3 = c3;
        const bool v1 = (j + 1 < j1), v2 = (j + 2 < j1), v3 = (j + 3 < j1);
        j += 4;
        if (j < j1) {
            c0 = csr[j];
            c1 = csr[min(j + 1, j1m)];
            c2 = csr[min(j + 2, j1m)];
            c3 = csr[min(j + 3, j1m)];
        }
        float a0 = as1g[s0 * 8 + hd], a1 = as1g[s1 * 8 + hd];
        float a2 = as1g[s2 * 8 + hd], a3 = as1g[s3 * 8 + hd];
        float g0 = h1[(size_t)s0 * 64 + l], g1 = h1[(size_t)s1 * 64 + l];
        float g2 = h1[(size_t)s2 * 64 + l], g3 = h1[(size_t)s3 * 64 + l];
        float e0 = a0 + ad; e0 = (e0 > 0.f) ? e0 : NEG_SLOPE * e0;
        float e1 = a1 + ad; e1 = (e1 > 0.f) ? e1 : NEG_SLOPE * e1;
        float e2 = a2 + ad; e2 = (e2 > 0.f) ? e2 : NEG_SLOPE * e2;
        float e3 = a3 + ad; e3 = (e3 > 0.f) ? e3 : NEG_SLOPE * e3;
        float x0 = __expf(e0);
        float x1 = v1 ? __expf(e1) : 0.f;
        float x2 = v2 ? __expf(e2) : 0.f;
        float x3 = v3 ? __expf(e3) : 0.f;
        den += (x0 + x1) + (x2 + x3);
        acc = fmaf(x0, g0, fmaf(x1, g1, fmaf(x2, g2, fmaf(x3, g3, acc))));
    }

    float v = acc / den + b1[l];
    v = (v > 0.f) ? v : expm1f(v);           // ELU
    rows[w][l] = v;                           // wave-private exchange (no barrier)

    float acc2 = 0.f;
    if (l < 40) {
#pragma unroll 8
        for (int k = 0; k < 64; ++k)
            acc2 = fmaf(rows[w][k], ws[k * 40 + l], acc2);
    }
    float ps = (l < 40) ? acc2 * a2s[l] : 0.f;
    float pd = (l < 40) ? acc2 * a2d[l] : 0.f;
#pragma unroll
    for (int off = 32; off; off >>= 1) {
        ps += __shfl_down(ps, off);
        pd += __shfl_down(pd, off);
    }
    if (l < 40) h2p[(size_t)wid * 48 + l] = acc2;
    if (l == 0) { as2[wid] = ps; ad2[wid] = pd; }
}

// ---------------------------------------------------------------------------
// K_agg2: layer-2 aggregate (4-wide pipelined) + bias + log_softmax(40)
// ---------------------------------------------------------------------------
__global__ __launch_bounds__(256) void k_agg2(
        const float* __restrict__ h2p, const float* __restrict__ as2,
        const float* __restrict__ ad2, const int* __restrict__ offs,
        const int* __restrict__ csr, const float* __restrict__ b2,
        float* __restrict__ out) {
    int wid = (blockIdx.x * 256 + threadIdx.x) >> 6;
    int l   = threadIdx.x & 63;
    if (wid >= N_NODES) return;
    const bool act = (l < 40);
    const float ad = ad2[wid];
    const int j0 = offs[wid], j1 = offs[wid + 1];
    const int j1m = j1 - 1;

    float acc = 0.f, den = 0.f;
    int c0 = csr[j0];
    int c1 = csr[min(j0 + 1, j1m)];
    int c2 = csr[min(j0 + 2, j1m)];
    int c3 = csr[min(j0 + 3, j1m)];
    for (int j = j0; j < j1; ) {
        const int s0 = c0, s1 = c1, s2 = c2, s3 = c3;
        const bool v1 = (j + 1 < j1), v2 = (j + 2 < j1), v3 = (j + 3 < j1);
        j += 4;
        if (j < j1) {
            c0 = csr[j];
            c1 = csr[min(j + 1, j1m)];
            c2 = csr[min(j + 2, j1m)];
            c3 = csr[min(j + 3, j1m)];
        }
        float a0 = as2[s0], a1 = as2[s1], a2 = as2[s2], a3 = as2[s3];
        float g0 = 0.f, g1 = 0.f, g2 = 0.f, g3 = 0.f;
        if (act) {
            g0 = h2p[(size_t)s0 * 48 + l];
            g1 = h2p[(size_t)s1 * 48 + l];
            g2 = h2p[(size_t)s2 * 48 + l];
            g3 = h2p[(size_t)s3 * 48 + l];
        }
        float e0 = a0 + ad; e0 = (e0 > 0.f) ? e0 : NEG_SLOPE * e0;
        float e1 = a1 + ad; e1 = (e1 > 0.f) ? e1 : NEG_SLOPE * e1;
        float e2 = a2 + ad; e2 = (e2 > 0.f) ? e2 : NEG_SLOPE * e2;
        float e3 = a3 + ad; e3 = (e3 > 0.f) ? e3 : NEG_SLOPE * e3;
        float x0 = __expf(e0);
        float x1 = v1 ? __expf(e1) : 0.f;
        float x2 = v2 ? __expf(e2) : 0.f;
        float x3 = v3 ? __expf(e3) : 0.f;
        den += (x0 + x1) + (x2 + x3);
        acc = fmaf(x0, g0, fmaf(x1, g1, fmaf(x2, g2, fmaf(x3, g3, acc))));
    }

    float v = act ? (acc / den + b2[l]) : -1e30f;
    float m = v;
#pragma unroll
    for (int off = 32; off; off >>= 1) m = fmaxf(m, __shfl_xor(m, off));
    float ex2 = act ? __expf(v - m) : 0.f;
    float s2 = ex2;
#pragma unroll
    for (int off = 32; off; off >>= 1) s2 += __shfl_xor(s2, off);
    if (act) out[(size_t)wid * 40 + l] = v - m - __logf(s2);
}

// ---------------------------------------------------------------------------
extern "C" void kernel_launch(void* const* d_in, const int* in_sizes, int n_in,
                              void* d_out, int out_size, void* d_ws, size_t ws_size,
                              hipStream_t stream) {
    const float* x   = (const float*)d_in[0];
    const void*  ei  = d_in[1];
    const float* W1  = (const float*)d_in[2];
    const float* a1s = (const float*)d_in[3];
    const float* a1d = (const float*)d_in[4];
    const float* b1  = (const float*)d_in[5];
    const float* W2  = (const float*)d_in[6];
    const float* a2s = (const float*)d_in[7];
    const float* a2d = (const float*)d_in[8];
    const float* b2  = (const float*)d_in[9];
    float* out = (float*)d_out;

    // workspace layout (floats)
    float* fws = (float*)d_ws;
    float* h1  = fws + 0;                     // 3,200,000
    float* as1 = fws + 3200000;               //   400,000
    float* ad1 = fws + 3600000;               //   400,000
    float* h2p = fws + 4000000;               // 2,400,000 (stride 48)
    float* as2 = fws + 6400000;               //    50,000
    float* ad2 = fws + 6450000;               //    50,000
    int*   offs   = (int*)(fws + 6500000);    // 50,001
    int*   cursor = offs + (N_NODES + 1);     // 50,000
    int*   csr    = cursor + N_NODES;         // 850,000
    int*   flag   = csr + E_TOT;              // 1

    hipMemsetAsync(offs, 0, (N_NODES + 1) * sizeof(int), stream);

    k_detect<<<1, 256, 0, stream>>>((const unsigned int*)ei, flag);

    int egrid = (E_TOT + 255) / 256;
    k_count<<<egrid, 256, 0, stream>>>(ei, flag, offs);
    k_scan<<<1, 1024, 0, stream>>>(offs, cursor);
    k_fill<<<egrid, 256, 0, stream>>>(ei, flag, cursor, csr);

    k1_transform<<<(N_NODES + 63) / 64, 256, 0, stream>>>(x, W1, a1s, a1d, h1, as1, ad1);

    int ngrid = (N_NODES + 3) / 4;
    k_agg1f<<<ngrid, 256, 0, stream>>>(h1, as1, ad1, offs, csr, b1,
                                       W2, a2s, a2d, h2p, as2, ad2);
    k_agg2<<<ngrid, 256, 0, stream>>>(h2p, as2, ad2, offs, csr, b2, out);
}

// Round 4
// 316.867 us; speedup vs baseline: 1.6224x; 1.2274x over previous
//
#include <hip/hip_runtime.h>
#include <hip/hip_bf16.h>
#include <math.h>

#define N_NODES 50000
#define E_EDGES 800000
#define E_TOT   850000   // + self loops
#define NEG_SLOPE 0.2f
#define SCAN_BLOCKS 49   // ceil(50001/1024)

// ---------------------------------------------------------------------------
// int64 vs int32 edge-index detection (values < 50000 -> int64 high words 0)
// ---------------------------------------------------------------------------
__global__ void k_detect(const unsigned int* __restrict__ ei, int* __restrict__ flag) {
    __shared__ int anynz;
    int t = threadIdx.x;
    if (t == 0) anynz = 0;
    __syncthreads();
    int nz = 0;
    for (int i = t; i < 2048; i += 256)
        nz |= (ei[2 * i + 1] != 0u);
    if (nz) atomicOr(&anynz, 1);
    __syncthreads();
    if (t == 0) *flag = (anynz == 0) ? 1 : 0;
}

__device__ __forceinline__ void edge_nodes(const void* ei, int is64, int e, int& s, int& d) {
    if (e >= E_EDGES) { s = d = e - E_EDGES; return; }   // self loop
    if (is64) {
        const long long* p = (const long long*)ei;
        s = (int)p[e]; d = (int)p[E_EDGES + e];
    } else {
        const int* p = (const int*)ei;
        s = p[e]; d = p[E_EDGES + e];
    }
}

// ---------------------------------------------------------------------------
// CSR build: histogram -> parallel scan -> fill
// ---------------------------------------------------------------------------
__global__ void k_count(const void* __restrict__ ei, const int* __restrict__ flag,
                        int* __restrict__ counts) {
    int e = blockIdx.x * 256 + threadIdx.x;
    if (e >= E_TOT) return;
    int s, d;
    edge_nodes(ei, *flag, e, s, d);
    atomicAdd(&counts[d], 1);
}

// block-local exclusive scan (in place) + per-block total
__global__ __launch_bounds__(1024) void k_scanA(int* __restrict__ offs,
                                                int* __restrict__ partials) {
    __shared__ int lds[1024];
    const int t   = threadIdx.x;
    const int idx = blockIdx.x * 1024 + t;
    int v = (idx <= N_NODES) ? offs[idx] : 0;
    lds[t] = v;
    __syncthreads();
    for (int off = 1; off < 1024; off <<= 1) {
        int u = (t >= off) ? lds[t - off] : 0;
        __syncthreads();
        lds[t] += u;
        __syncthreads();
    }
    int incl = lds[t];
    if (idx <= N_NODES) offs[idx] = incl - v;         // exclusive within chunk
    if (t == 1023) partials[blockIdx.x] = incl;       // chunk total
}

// add scanned partials prefix; emit final offs + cursor copy
__global__ __launch_bounds__(1024) void k_scanC(int* __restrict__ offs,
                                                const int* __restrict__ partials,
                                                int* __restrict__ cursor) {
    __shared__ int sprefix;
    const int t   = threadIdx.x;
    const int bid = blockIdx.x;
    if (t < 64) {
        int p = (t < bid) ? partials[t] : 0;          // bid <= 48 < 64
#pragma unroll
        for (int off = 32; off; off >>= 1) p += __shfl_down(p, off);
        if (t == 0) sprefix = p;
    }
    __syncthreads();
    const int idx = bid * 1024 + t;
    if (idx <= N_NODES) {
        int v = offs[idx] + sprefix;
        offs[idx] = v;
        if (idx < N_NODES) cursor[idx] = v;
    }
}

__global__ void k_fill(const void* __restrict__ ei, const int* __restrict__ flag,
                       int* __restrict__ cursor, int* __restrict__ csr_src) {
    int e = blockIdx.x * 256 + threadIdx.x;
    if (e >= E_TOT) return;
    int s, d;
    edge_nodes(ei, *flag, e, s, d);
    int pos = atomicAdd(&cursor[d], 1);
    csr_src[pos] = s;
}

// ---------------------------------------------------------------------------
// K1: h1 = x @ W1 (50000x128 @ 128x64) + per-node attention halves
// ---------------------------------------------------------------------------
__global__ __launch_bounds__(256) void k1_transform(
        const float* __restrict__ x, const float* __restrict__ W1,
        const float* __restrict__ a1s, const float* __restrict__ a1d,
        float* __restrict__ h1, float* __restrict__ as1, float* __restrict__ ad1) {
    __shared__ float ws[128 * 64];
    __shared__ float xs[64 * 132];
    const int t  = threadIdx.x;
    const int nb = blockIdx.x * 64;
    for (int i = t * 4; i < 128 * 64; i += 1024)
        *(float4*)&ws[i] = *(const float4*)&W1[i];
    for (int i = t * 4; i < 64 * 128; i += 1024) {
        int n = i >> 7, k = i & 127;
        float4 v = make_float4(0.f, 0.f, 0.f, 0.f);
        if (nb + n < N_NODES) v = *(const float4*)&x[(size_t)(nb + n) * 128 + k];
        *(float4*)&xs[n * 132 + k] = v;
    }
    __syncthreads();

    const int oq = t & 15;
    const int nq = t >> 4;
    float4 acc[4];
#pragma unroll
    for (int i = 0; i < 4; ++i) acc[i] = make_float4(0.f, 0.f, 0.f, 0.f);

    for (int k = 0; k < 128; k += 4) {
        float4 wv0 = *(float4*)&ws[(k + 0) * 64 + oq * 4];
        float4 wv1 = *(float4*)&ws[(k + 1) * 64 + oq * 4];
        float4 wv2 = *(float4*)&ws[(k + 2) * 64 + oq * 4];
        float4 wv3 = *(float4*)&ws[(k + 3) * 64 + oq * 4];
#pragma unroll
        for (int i = 0; i < 4; ++i) {
            float4 xv = *(float4*)&xs[(nq * 4 + i) * 132 + k];
            acc[i].x += xv.x * wv0.x + xv.y * wv1.x + xv.z * wv2.x + xv.w * wv3.x;
            acc[i].y += xv.x * wv0.y + xv.y * wv1.y + xv.z * wv2.y + xv.w * wv3.y;
            acc[i].z += xv.x * wv0.z + xv.y * wv1.z + xv.z * wv2.z + xv.w * wv3.z;
            acc[i].w += xv.x * wv0.w + xv.y * wv1.w + xv.z * wv2.w + xv.w * wv3.w;
        }
    }
    __syncthreads();
#pragma unroll
    for (int i = 0; i < 4; ++i) {
        int n = nq * 4 + i;
        *(float4*)&xs[n * 68 + oq * 4] = acc[i];
        if (nb + n < N_NODES)
            *(float4*)&h1[(size_t)(nb + n) * 64 + oq * 4] = acc[i];
    }
    __syncthreads();
    for (int p = t; p < 512; p += 256) {
        int n = p >> 3, hd = p & 7;
        float ss = 0.f, dd = 0.f;
#pragma unroll
        for (int o = 0; o < 8; ++o) {
            float hv = xs[n * 68 + hd * 8 + o];
            ss += hv * a1s[hd * 8 + o];
            dd += hv * a1d[hd * 8 + o];
        }
        if (nb + n < N_NODES) {
            as1[(nb + n) * 8 + hd] = ss;
            ad1[(nb + n) * 8 + hd] = dd;
        }
    }
}

// ---------------------------------------------------------------------------
// K_agg1 (fused with layer-2 transform): 8-wide pipelined gathers
// ---------------------------------------------------------------------------
__global__ __launch_bounds__(256) void k_agg1f(
        const float* __restrict__ h1, const float* __restrict__ as1g,
        const float* __restrict__ ad1g, const int* __restrict__ offs,
        const int* __restrict__ csr, const float* __restrict__ b1,
        const float* __restrict__ W2, const float* __restrict__ a2s,
        const float* __restrict__ a2d,
        float* __restrict__ h2p, float* __restrict__ as2, float* __restrict__ ad2) {
    __shared__ float ws[64 * 40];            // 10 KB
    __shared__ float rows[4][64];
    const int t = threadIdx.x;
    for (int i = t; i < 64 * 40; i += 256) ws[i] = W2[i];
    __syncthreads();

    const int w = t >> 6, l = t & 63;
    const int wid = blockIdx.x * 4 + w;
    if (wid >= N_NODES) return;
    const int hd = l >> 3;
    const float ad = ad1g[wid * 8 + hd];
    const int j0 = offs[wid], j1 = offs[wid + 1];
    const int j1m = j1 - 1;

    float acc = 0.f, den = 0.f;
    int c[8];
#pragma unroll
    for (int i = 0; i < 8; ++i) c[i] = csr[min(j0 + i, j1m)];
    for (int j = j0; j < j1; ) {
        int s[8];
#pragma unroll
        for (int i = 0; i < 8; ++i) s[i] = c[i];
        const int rem = j1 - j;
        j += 8;
        if (j < j1) {
#pragma unroll
            for (int i = 0; i < 8; ++i) c[i] = csr[min(j + i, j1m)];
        }
        float a[8], g[8];
#pragma unroll
        for (int i = 0; i < 8; ++i) a[i] = as1g[s[i] * 8 + hd];
#pragma unroll
        for (int i = 0; i < 8; ++i) g[i] = h1[(size_t)s[i] * 64 + l];
#pragma unroll
        for (int i = 0; i < 8; ++i) {
            float e = a[i] + ad;
            e = (e > 0.f) ? e : NEG_SLOPE * e;
            float xp = (i < rem) ? __expf(e) : 0.f;
            den += xp;
            acc = fmaf(xp, g[i], acc);
        }
    }

    float v = acc / den + b1[l];
    v = (v > 0.f) ? v : expm1f(v);           // ELU
    rows[w][l] = v;                           // wave-private exchange

    float acc2 = 0.f;
    if (l < 40) {
#pragma unroll 8
        for (int k = 0; k < 64; ++k)
            acc2 = fmaf(rows[w][k], ws[k * 40 + l], acc2);
    }
    float ps = (l < 40) ? acc2 * a2s[l] : 0.f;
    float pd = (l < 40) ? acc2 * a2d[l] : 0.f;
#pragma unroll
    for (int off = 32; off; off >>= 1) {
        ps += __shfl_down(ps, off);
        pd += __shfl_down(pd, off);
    }
    if (l < 40) h2p[(size_t)wid * 48 + l] = acc2;
    if (l == 0) { as2[wid] = ps; ad2[wid] = pd; }
}

// ---------------------------------------------------------------------------
// K_agg2: layer-2 aggregate (8-wide pipelined) + bias + log_softmax(40)
// ---------------------------------------------------------------------------
__global__ __launch_bounds__(256) void k_agg2(
        const float* __restrict__ h2p, const float* __restrict__ as2,
        const float* __restrict__ ad2, const int* __restrict__ offs,
        const int* __restrict__ csr, const float* __restrict__ b2,
        float* __restrict__ out) {
    int wid = (blockIdx.x * 256 + threadIdx.x) >> 6;
    int l   = threadIdx.x & 63;
    if (wid >= N_NODES) return;
    const bool act = (l < 40);
    const float ad = ad2[wid];
    const int j0 = offs[wid], j1 = offs[wid + 1];
    const int j1m = j1 - 1;

    float acc = 0.f, den = 0.f;
    int c[8];
#pragma unroll
    for (int i = 0; i < 8; ++i) c[i] = csr[min(j0 + i, j1m)];
    for (int j = j0; j < j1; ) {
        int s[8];
#pragma unroll
        for (int i = 0; i < 8; ++i) s[i] = c[i];
        const int rem = j1 - j;
        j += 8;
        if (j < j1) {
#pragma unroll
            for (int i = 0; i < 8; ++i) c[i] = csr[min(j + i, j1m)];
        }
        float a[8], g[8];
#pragma unroll
        for (int i = 0; i < 8; ++i) a[i] = as2[s[i]];
#pragma unroll
        for (int i = 0; i < 8; ++i) g[i] = act ? h2p[(size_t)s[i] * 48 + l] : 0.f;
#pragma unroll
        for (int i = 0; i < 8; ++i) {
            float e = a[i] + ad;
            e = (e > 0.f) ? e : NEG_SLOPE * e;
            float xp = (i < rem) ? __expf(e) : 0.f;
            den += xp;
            acc = fmaf(xp, g[i], acc);
        }
    }

    float v = act ? (acc / den + b2[l]) : -1e30f;
    float m = v;
#pragma unroll
    for (int off = 32; off; off >>= 1) m = fmaxf(m, __shfl_xor(m, off));
    float ex2 = act ? __expf(v - m) : 0.f;
    float s2 = ex2;
#pragma unroll
    for (int off = 32; off; off >>= 1) s2 += __shfl_xor(s2, off);
    if (act) out[(size_t)wid * 40 + l] = v - m - __logf(s2);
}

// ---------------------------------------------------------------------------
extern "C" void kernel_launch(void* const* d_in, const int* in_sizes, int n_in,
                              void* d_out, int out_size, void* d_ws, size_t ws_size,
                              hipStream_t stream) {
    const float* x   = (const float*)d_in[0];
    const void*  ei  = d_in[1];
    const float* W1  = (const float*)d_in[2];
    const float* a1s = (const float*)d_in[3];
    const float* a1d = (const float*)d_in[4];
    const float* b1  = (const float*)d_in[5];
    const float* W2  = (const float*)d_in[6];
    const float* a2s = (const float*)d_in[7];
    const float* a2d = (const float*)d_in[8];
    const float* b2  = (const float*)d_in[9];
    float* out = (float*)d_out;

    // workspace layout (floats)
    float* fws = (float*)d_ws;
    float* h1  = fws + 0;                     // 3,200,000
    float* as1 = fws + 3200000;               //   400,000
    float* ad1 = fws + 3600000;               //   400,000
    float* h2p = fws + 4000000;               // 2,400,000 (stride 48)
    float* as2 = fws + 6400000;               //    50,000
    float* ad2 = fws + 6450000;               //    50,000
    int*   offs     = (int*)(fws + 6500000);  // 50,001
    int*   cursor   = offs + (N_NODES + 1);   // 50,000
    int*   csr      = cursor + N_NODES;       // 850,000
    int*   flag     = csr + E_TOT;            // 1
    int*   partials = flag + 1;               // 49

    hipMemsetAsync(offs, 0, (N_NODES + 1) * sizeof(int), stream);

    k_detect<<<1, 256, 0, stream>>>((const unsigned int*)ei, flag);

    int egrid = (E_TOT + 255) / 256;
    k_count<<<egrid, 256, 0, stream>>>(ei, flag, offs);
    k_scanA<<<SCAN_BLOCKS, 1024, 0, stream>>>(offs, partials);
    k_scanC<<<SCAN_BLOCKS, 1024, 0, stream>>>(offs, partials, cursor);
    k_fill<<<egrid, 256, 0, stream>>>(ei, flag, cursor, csr);

    k1_transform<<<(N_NODES + 63) / 64, 256, 0, stream>>>(x, W1, a1s, a1d, h1, as1, ad1);

    int ngrid = (N_NODES + 3) / 4;
    k_agg1f<<<ngrid, 256, 0, stream>>>(h1, as1, ad1, offs, csr, b1,
                                       W2, a2s, a2d, h2p, as2, ad2);
    k_agg2<<<ngrid, 256, 0, stream>>>(h2p, as2, ad2, offs, csr, b2, out);
}

// Round 5
// 300.185 us; speedup vs baseline: 1.7125x; 1.0556x over previous
//
#include <hip/hip_runtime.h>
#include <hip/hip_bf16.h>
#include <math.h>

#define N_NODES 50000
#define E_EDGES 800000
#define E_TOT   850000   // + self loops
#define NEG_SLOPE 0.2f
#define SCAN_BLOCKS 49   // ceil(50001/1024)

// ---------------------------------------------------------------------------
// Fused: zero offs histogram + int64/int32 edge-index detection
// (values < 50000 -> int64 high words all zero)
// ---------------------------------------------------------------------------
__global__ __launch_bounds__(256) void k_detect0(const unsigned int* __restrict__ ei,
                                                 int* __restrict__ flag,
                                                 int* __restrict__ offs) {
    int gid = blockIdx.x * 256 + threadIdx.x;
    for (int i = gid; i <= N_NODES; i += gridDim.x * 256) offs[i] = 0;
    if (blockIdx.x == 0) {
        __shared__ int anynz;
        if (threadIdx.x == 0) anynz = 0;
        __syncthreads();
        int nz = 0;
        for (int i = threadIdx.x; i < 2048; i += 256)
            nz |= (ei[2 * i + 1] != 0u);
        if (nz) atomicOr(&anynz, 1);
        __syncthreads();
        if (threadIdx.x == 0) *flag = (anynz == 0) ? 1 : 0;
    }
}

__device__ __forceinline__ void edge_nodes(const void* ei, int is64, int e, int& s, int& d) {
    if (e >= E_EDGES) { s = d = e - E_EDGES; return; }   // self loop
    if (is64) {
        const long long* p = (const long long*)ei;
        s = (int)p[e]; d = (int)p[E_EDGES + e];
    } else {
        const int* p = (const int*)ei;
        s = p[e]; d = p[E_EDGES + e];
    }
}

// ---------------------------------------------------------------------------
// CSR build: histogram -> parallel scan -> fill (+16 zero-pad entries)
// ---------------------------------------------------------------------------
__global__ void k_count(const void* __restrict__ ei, const int* __restrict__ flag,
                        int* __restrict__ counts) {
    int e = blockIdx.x * 256 + threadIdx.x;
    if (e >= E_TOT) return;
    int s, d;
    edge_nodes(ei, *flag, e, s, d);
    atomicAdd(&counts[d], 1);
}

// block-local exclusive scan (in place) + per-block total
__global__ __launch_bounds__(1024) void k_scanA(int* __restrict__ offs,
                                                int* __restrict__ partials) {
    __shared__ int lds[1024];
    const int t   = threadIdx.x;
    const int idx = blockIdx.x * 1024 + t;
    int v = (idx <= N_NODES) ? offs[idx] : 0;
    lds[t] = v;
    __syncthreads();
    for (int off = 1; off < 1024; off <<= 1) {
        int u = (t >= off) ? lds[t - off] : 0;
        __syncthreads();
        lds[t] += u;
        __syncthreads();
    }
    int incl = lds[t];
    if (idx <= N_NODES) offs[idx] = incl - v;         // exclusive within chunk
    if (t == 1023) partials[blockIdx.x] = incl;       // chunk total
}

// add scanned partials prefix; emit final offs + cursor copy
__global__ __launch_bounds__(1024) void k_scanC(int* __restrict__ offs,
                                                const int* __restrict__ partials,
                                                int* __restrict__ cursor) {
    __shared__ int sprefix;
    const int t   = threadIdx.x;
    const int bid = blockIdx.x;
    if (t < 64) {
        int p = (t < bid) ? partials[t] : 0;          // bid <= 48 < 64
#pragma unroll
        for (int off = 32; off; off >>= 1) p += __shfl_down(p, off);
        if (t == 0) sprefix = p;
    }
    __syncthreads();
    const int idx = bid * 1024 + t;
    if (idx <= N_NODES) {
        int v = offs[idx] + sprefix;
        offs[idx] = v;
        if (idx < N_NODES) cursor[idx] = v;
    }
}

__global__ void k_fill(const void* __restrict__ ei, const int* __restrict__ flag,
                       int* __restrict__ cursor, int* __restrict__ csr_src) {
    int e = blockIdx.x * 256 + threadIdx.x;
    if (e < 16) csr_src[E_TOT + e] = 0;               // pad (valid node id 0)
    if (e >= E_TOT) return;
    int s, d;
    edge_nodes(ei, *flag, e, s, d);
    int pos = atomicAdd(&cursor[d], 1);
    csr_src[pos] = s;
}

// ---------------------------------------------------------------------------
// K1: h1 = x @ W1 (50000x128 @ 128x64) + per-node attention halves
// ---------------------------------------------------------------------------
__global__ __launch_bounds__(256) void k1_transform(
        const float* __restrict__ x, const float* __restrict__ W1,
        const float* __restrict__ a1s, const float* __restrict__ a1d,
        float* __restrict__ h1, float* __restrict__ as1, float* __restrict__ ad1) {
    __shared__ float ws[128 * 64];
    __shared__ float xs[64 * 132];
    const int t  = threadIdx.x;
    const int nb = blockIdx.x * 64;
    for (int i = t * 4; i < 128 * 64; i += 1024)
        *(float4*)&ws[i] = *(const float4*)&W1[i];
    for (int i = t * 4; i < 64 * 128; i += 1024) {
        int n = i >> 7, k = i & 127;
        float4 v = make_float4(0.f, 0.f, 0.f, 0.f);
        if (nb + n < N_NODES) v = *(const float4*)&x[(size_t)(nb + n) * 128 + k];
        *(float4*)&xs[n * 132 + k] = v;
    }
    __syncthreads();

    const int oq = t & 15;
    const int nq = t >> 4;
    float4 acc[4];
#pragma unroll
    for (int i = 0; i < 4; ++i) acc[i] = make_float4(0.f, 0.f, 0.f, 0.f);

    for (int k = 0; k < 128; k += 4) {
        float4 wv0 = *(float4*)&ws[(k + 0) * 64 + oq * 4];
        float4 wv1 = *(float4*)&ws[(k + 1) * 64 + oq * 4];
        float4 wv2 = *(float4*)&ws[(k + 2) * 64 + oq * 4];
        float4 wv3 = *(float4*)&ws[(k + 3) * 64 + oq * 4];
#pragma unroll
        for (int i = 0; i < 4; ++i) {
            float4 xv = *(float4*)&xs[(nq * 4 + i) * 132 + k];
            acc[i].x += xv.x * wv0.x + xv.y * wv1.x + xv.z * wv2.x + xv.w * wv3.x;
            acc[i].y += xv.x * wv0.y + xv.y * wv1.y + xv.z * wv2.y + xv.w * wv3.y;
            acc[i].z += xv.x * wv0.z + xv.y * wv1.z + xv.z * wv2.z + xv.w * wv3.z;
            acc[i].w += xv.x * wv0.w + xv.y * wv1.w + xv.z * wv2.w + xv.w * wv3.w;
        }
    }
    __syncthreads();
#pragma unroll
    for (int i = 0; i < 4; ++i) {
        int n = nq * 4 + i;
        *(float4*)&xs[n * 68 + oq * 4] = acc[i];
        if (nb + n < N_NODES)
            *(float4*)&h1[(size_t)(nb + n) * 64 + oq * 4] = acc[i];
    }
    __syncthreads();
    for (int p = t; p < 512; p += 256) {
        int n = p >> 3, hd = p & 7;
        float ss = 0.f, dd = 0.f;
#pragma unroll
        for (int o = 0; o < 8; ++o) {
            float hv = xs[n * 68 + hd * 8 + o];
            ss += hv * a1s[hd * 8 + o];
            dd += hv * a1d[hd * 8 + o];
        }
        if (nb + n < N_NODES) {
            as1[(nb + n) * 8 + hd] = ss;
            ad1[(nb + n) * 8 + hd] = dd;
        }
    }
}

// ---------------------------------------------------------------------------
// K_agg1 (fused with layer-2 transform): 8-wide gathers, main/tail split,
// 32-bit indices, scalar loop bounds.
// ---------------------------------------------------------------------------
__global__ __launch_bounds__(256) void k_agg1f(
        const float* __restrict__ h1, const float* __restrict__ as1g,
        const float* __restrict__ ad1g, const int* __restrict__ offs,
        const int* __restrict__ csr, const float* __restrict__ b1,
        const float* __restrict__ W2, const float* __restrict__ a2s,
        const float* __restrict__ a2d,
        float* __restrict__ h2p, float* __restrict__ as2, float* __restrict__ ad2) {
    __shared__ float ws[64 * 40];            // 10 KB
    __shared__ float rows[4][64];
    const int t = threadIdx.x;
    for (int i = t; i < 64 * 40; i += 256) ws[i] = W2[i];
    __syncthreads();

    const int w = t >> 6, l = t & 63;
    const int wid = blockIdx.x * 4 + w;
    if (wid >= N_NODES) return;
    const int hd = l >> 3;
    const float ad = ad1g[wid * 8 + hd];
    const int j0 = __builtin_amdgcn_readfirstlane(offs[wid]);
    const int j1 = __builtin_amdgcn_readfirstlane(offs[wid + 1]);

    float acc = 0.f, den = 0.f;
    int c[8];
#pragma unroll
    for (int i = 0; i < 8; ++i) c[i] = csr[j0 + i];   // pad makes overread safe
    int j = j0;
    while (j + 8 <= j1) {                             // full groups: no predication
        int s[8];
#pragma unroll
        for (int i = 0; i < 8; ++i) s[i] = c[i];
#pragma unroll
        for (int i = 0; i < 8; ++i) c[i] = csr[j + 8 + i];
        float a[8], g[8];
#pragma unroll
        for (int i = 0; i < 8; ++i) a[i] = as1g[(unsigned)s[i] * 8u + (unsigned)hd];
#pragma unroll
        for (int i = 0; i < 8; ++i) g[i] = h1[(unsigned)s[i] * 64u + (unsigned)l];
#pragma unroll
        for (int i = 0; i < 8; ++i) {
            float e = a[i] + ad;
            e = fmaxf(e, NEG_SLOPE * e);              // leaky relu, 2 ops
            float xp = __expf(e);
            den += xp;
            acc = fmaf(xp, g[i], acc);
        }
        j += 8;
    }
    const int rem = j1 - j;                            // 0..7
    if (rem) {
        float a[8], g[8];
#pragma unroll
        for (int i = 0; i < 8; ++i) a[i] = as1g[(unsigned)c[i] * 8u + (unsigned)hd];
#pragma unroll
        for (int i = 0; i < 8; ++i) g[i] = h1[(unsigned)c[i] * 64u + (unsigned)l];
#pragma unroll
        for (int i = 0; i < 8; ++i) {
            float e = a[i] + ad;
            e = fmaxf(e, NEG_SLOPE * e);
            float xp = (i < rem) ? __expf(e) : 0.f;
            den += xp;
            acc = fmaf(xp, g[i], acc);
        }
    }

    float v = acc / den + b1[l];
    v = (v > 0.f) ? v : expm1f(v);           // ELU
    rows[w][l] = v;                           // wave-private exchange

    float acc2 = 0.f;
    if (l < 40) {
#pragma unroll 8
        for (int k = 0; k < 64; ++k)
            acc2 = fmaf(rows[w][k], ws[k * 40 + l], acc2);
    }
    float ps = (l < 40) ? acc2 * a2s[l] : 0.f;
    float pd = (l < 40) ? acc2 * a2d[l] : 0.f;
#pragma unroll
    for (int off = 32; off; off >>= 1) {
        ps += __shfl_down(ps, off);
        pd += __shfl_down(pd, off);
    }
    if (l < 40) h2p[(unsigned)wid * 48u + (unsigned)l] = acc2;
    if (l == 0) { as2[wid] = ps; ad2[wid] = pd; }
}

// ---------------------------------------------------------------------------
// K_agg2: layer-2 aggregate, same structure + bias + log_softmax(40)
// ---------------------------------------------------------------------------
__global__ __launch_bounds__(256) void k_agg2(
        const float* __restrict__ h2p, const float* __restrict__ as2,
        const float* __restrict__ ad2, const int* __restrict__ offs,
        const int* __restrict__ csr, const float* __restrict__ b2,
        float* __restrict__ out) {
    int wid = (blockIdx.x * 256 + threadIdx.x) >> 6;
    int l   = threadIdx.x & 63;
    if (wid >= N_NODES) return;
    const bool act = (l < 40);
    const float ad = ad2[wid];
    const int j0 = __builtin_amdgcn_readfirstlane(offs[wid]);
    const int j1 = __builtin_amdgcn_readfirstlane(offs[wid + 1]);

    float acc = 0.f, den = 0.f;
    int c[8];
#pragma unroll
    for (int i = 0; i < 8; ++i) c[i] = csr[j0 + i];
    int j = j0;
    while (j + 8 <= j1) {
        int s[8];
#pragma unroll
        for (int i = 0; i < 8; ++i) s[i] = c[i];
#pragma unroll
        for (int i = 0; i < 8; ++i) c[i] = csr[j + 8 + i];
        float a[8], g[8];
#pragma unroll
        for (int i = 0; i < 8; ++i) a[i] = as2[s[i]];
#pragma unroll
        for (int i = 0; i < 8; ++i) g[i] = act ? h2p[(unsigned)s[i] * 48u + (unsigned)l] : 0.f;
#pragma unroll
        for (int i = 0; i < 8; ++i) {
            float e = a[i] + ad;
            e = fmaxf(e, NEG_SLOPE * e);
            float xp = __expf(e);
            den += xp;
            acc = fmaf(xp, g[i], acc);
        }
        j += 8;
    }
    const int rem = j1 - j;
    if (rem) {
        float a[8], g[8];
#pragma unroll
        for (int i = 0; i < 8; ++i) a[i] = as2[c[i]];
#pragma unroll
        for (int i = 0; i < 8; ++i) g[i] = act ? h2p[(unsigned)c[i] * 48u + (unsigned)l] : 0.f;
#pragma unroll
        for (int i = 0; i < 8; ++i) {
            float e = a[i] + ad;
            e = fmaxf(e, NEG_SLOPE * e);
            float xp = (i < rem) ? __expf(e) : 0.f;
            den += xp;
            acc = fmaf(xp, g[i], acc);
        }
    }

    float v = act ? (acc / den + b2[l]) : -1e30f;
    float m = v;
#pragma unroll
    for (int off = 32; off; off >>= 1) m = fmaxf(m, __shfl_xor(m, off));
    float ex2 = act ? __expf(v - m) : 0.f;
    float s2 = ex2;
#pragma unroll
    for (int off = 32; off; off >>= 1) s2 += __shfl_xor(s2, off);
    if (act) out[(size_t)wid * 40 + l] = v - m - __logf(s2);
}

// ---------------------------------------------------------------------------
extern "C" void kernel_launch(void* const* d_in, const int* in_sizes, int n_in,
                              void* d_out, int out_size, void* d_ws, size_t ws_size,
                              hipStream_t stream) {
    const float* x   = (const float*)d_in[0];
    const void*  ei  = d_in[1];
    const float* W1  = (const float*)d_in[2];
    const float* a1s = (const float*)d_in[3];
    const float* a1d = (const float*)d_in[4];
    const float* b1  = (const float*)d_in[5];
    const float* W2  = (const float*)d_in[6];
    const float* a2s = (const float*)d_in[7];
    const float* a2d = (const float*)d_in[8];
    const float* b2  = (const float*)d_in[9];
    float* out = (float*)d_out;

    // workspace layout (floats)
    float* fws = (float*)d_ws;
    float* h1  = fws + 0;                     // 3,200,000
    float* as1 = fws + 3200000;               //   400,000
    float* ad1 = fws + 3600000;               //   400,000
    float* h2p = fws + 4000000;               // 2,400,000 (stride 48)
    float* as2 = fws + 6400000;               //    50,000
    float* ad2 = fws + 6450000;               //    50,000
    int*   offs     = (int*)(fws + 6500000);  // 50,001
    int*   cursor   = offs + (N_NODES + 1);   // 50,000
    int*   csr      = cursor + N_NODES;       // 850,000 + 16 pad
    int*   partials = csr + E_TOT + 16;       // 49
    int*   flag     = partials + SCAN_BLOCKS; // 1

    k_detect0<<<64, 256, 0, stream>>>((const unsigned int*)ei, flag, offs);

    int egrid = (E_TOT + 255) / 256;
    k_count<<<egrid, 256, 0, stream>>>(ei, flag, offs);
    k_scanA<<<SCAN_BLOCKS, 1024, 0, stream>>>(offs, partials);
    k_scanC<<<SCAN_BLOCKS, 1024, 0, stream>>>(offs, partials, cursor);
    k_fill<<<egrid, 256, 0, stream>>>(ei, flag, cursor, csr);

    k1_transform<<<(N_NODES + 63) / 64, 256, 0, stream>>>(x, W1, a1s, a1d, h1, as1, ad1);

    int ngrid = (N_NODES + 3) / 4;
    k_agg1f<<<ngrid, 256, 0, stream>>>(h1, as1, ad1, offs, csr, b1,
                                       W2, a2s, a2d, h2p, as2, ad2);
    k_agg2<<<ngrid, 256, 0, stream>>>(h2p, as2, ad2, offs, csr, b2, out);
}